// Round 4
// baseline (499.553 us; speedup 1.0000x reference)
//
#include <hip/hip_runtime.h>
#include <hip/hip_bf16.h>
#include <math.h>

// Problem constants
#define B_ 32
#define T_ 4096
#define QD_ 1024
#define MD_ 512
#define AD_ 128
#define F_ 32
#define K_ 31
#define PAD_ 15

#define TT 128            // timesteps per block (4 waves x 32 rows)
#define NBLK (T_ / TT)    // 32 t-blocks per batch

typedef float f32x16 __attribute__((ext_vector_type(16)));
typedef unsigned int uint4v __attribute__((ext_vector_type(4)));

// round-half-up float->bf16 pair packed in one VGPR via v_perm
__device__ inline unsigned pk_bf2(float lo, float hi) {
    unsigned ul = __float_as_uint(lo) + 0x8000u;
    unsigned uh = __float_as_uint(hi) + 0x8000u;
    return __builtin_amdgcn_perm(uh, ul, 0x07060302u);
}

__device__ inline unsigned short f2bf_rn(float f) {
    unsigned u = __float_as_uint(f);
    u += 0x7fffu + ((u >> 16) & 1u);
    return (unsigned short)(u >> 16);
}

__device__ inline float bf2f(unsigned short u) {
    return __uint_as_float(((unsigned)u) << 16);
}

// v_mfma via inline asm. s_nop 1 covers VALU-write -> MFMA-read hazard.
__device__ inline void mfma32(f32x16& c, uint4v a, uint4v b) {
    asm("s_nop 1\n\tv_mfma_f32_32x32x16_bf16 %0, %1, %2, %0"
        : "+v"(c) : "v"(a), "v"(b));
}

__device__ inline float fast_tanh(float x) {
    // 1 - 2/(e^{2x}+1); exact limits at +-inf, no NaN for finite x
    float e = __expf(2.f * x);
    return 1.f - 2.f / (e + 1.f);
}

// ---------------- K0: swizzle Wm -> bf16 MFMA-fragment order ----------------
// wmT_sw[((kk*4 + ct)*64 + lane)*8 + j] = bf16(Wm[kk*16 + (lane>>5)*8 + j][ct*32 + (lane&31)])
__global__ __launch_bounds__(256) void k_prep(const float* __restrict__ Wm,
                                              unsigned short* __restrict__ wmT_sw) {
    int gid = blockIdx.x * 256 + threadIdx.x;   // 0..8191
    int kk = gid >> 8;
    int ct = (gid >> 6) & 3;
    int lane = gid & 63;
    int k0 = kk * 16 + (lane >> 5) * 8;
    int a = ct * 32 + (lane & 31);
    unsigned short o[8];
#pragma unroll
    for (int j = 0; j < 8; j++) o[j] = f2bf_rn(Wm[(k0 + j) * AD_ + a]);
    uint4v v;
    v[0] = ((unsigned)o[1] << 16) | o[0];
    v[1] = ((unsigned)o[3] << 16) | o[2];
    v[2] = ((unsigned)o[5] << 16) | o[4];
    v[3] = ((unsigned)o[7] << 16) | o[6];
    *(uint4v*)(wmT_sw + (long)gid * 8) = v;
}

// ---------------- K1: processed query ----------------
__global__ __launch_bounds__(128) void k_pq(const float* __restrict__ query,
                                            const float* __restrict__ Wq,
                                            float* __restrict__ pq) {
    int b = blockIdx.x;
    int qc = blockIdx.y;
    int a = threadIdx.x;
    const float* qrow = query + b * QD_ + qc * 128;
    const float* wq = Wq + (qc * 128) * AD_ + a;
    float acc = 0.f;
#pragma unroll 4
    for (int i = 0; i < 128; i++) acc += qrow[i] * wq[i * AD_];
    atomicAdd(&pq[b * AD_ + a], acc);
}

// ---------------- K2: fused conv + base + barrier-free MFMA K-loop + context ----
__global__ __launch_bounds__(256, 3) void k_score_ctx(
    const float* __restrict__ memory, const float* __restrict__ alignments,
    const unsigned char* __restrict__ mask,
    const unsigned short* __restrict__ wmT_sw, const float* __restrict__ bm,
    const float* __restrict__ convw, const float* __restrict__ convb,
    const float* __restrict__ Wl, const float* __restrict__ bl,
    const float* __restrict__ vw, const float* __restrict__ vb,
    const float* __restrict__ pq, const float* __restrict__ bq,
    float* __restrict__ scores, float* __restrict__ bmax,
    float* __restrict__ bden, float* __restrict__ num) {
    __shared__ __align__(16) unsigned short s_base[TT * AD_];     // 32768 B
    __shared__ __align__(16) float s_loc[TT * F_];                // 16384 B
    __shared__ __align__(16) float s_align[(TT + K_ - 1) * 2 + 2];// ~1280 B
    __shared__ float s_score[TT];
    __shared__ float s_w[TT];

    const int tid = threadIdx.x;
    const int b = blockIdx.y;
    const int blk = blockIdx.x;
    const int t0 = blk * TT;

    const int lane = tid & 63;
    const int w = tid >> 6;
    const int half = lane >> 5;
    const int l31 = lane & 31;

    // ---- issue first two A-chunk loads early (overlap with phase 1) ----
    const float* aRow = memory + ((long)(b * T_ + t0 + w * 32 + l31)) * MD_ + half * 8;
    float4 p00 = *(const float4*)(aRow + 0);
    float4 p01 = *(const float4*)(aRow + 4);
    float4 p02 = *(const float4*)(aRow + 16);
    float4 p03 = *(const float4*)(aRow + 20);
    float4 p10 = *(const float4*)(aRow + 32);
    float4 p11 = *(const float4*)(aRow + 36);
    float4 p12 = *(const float4*)(aRow + 48);
    float4 p13 = *(const float4*)(aRow + 52);

    // ---- stage alignment window ----
    for (int i = tid; i < (TT + K_ - 1) * 2; i += 256) {
        int tg = t0 + (i >> 1) - PAD_;
        s_align[i] = (tg >= 0 && tg < T_) ? alignments[((long)b * T_ + tg) * 2 + (i & 1)] : 0.f;
    }
    __syncthreads();

    // ---- location conv: thread owns f = tid&31, t-range (tid>>5)*16..+15 ----
    {
        const int f = tid & 31;
        const int tg = tid >> 5;
        float accv[16];
        float cb = convb[f];
#pragma unroll
        for (int j = 0; j < 16; j++) accv[j] = cb;
        const float* w0 = convw + f * (2 * K_);
        const float* w1 = w0 + K_;
        for (int k = 0; k < K_; k++) {
            float wa = w0[k], wb = w1[k];
            const float2* al = (const float2*)&s_align[0] + (tg * 16 + k);
#pragma unroll
            for (int j = 0; j < 16; j++) {
                float2 v = al[j];
                accv[j] += v.x * wa + v.y * wb;
            }
        }
#pragma unroll
        for (int j = 0; j < 16; j++) s_loc[(tg * 16 + j) * F_ + f] = accv[j];
    }
    __syncthreads();

    // ---- base[t][a] = pq + bq + bm + bl + loc @ Wl -> bf16 LDS ----
    {
        const int a = tid & 127;
        float cbase = pq[b * AD_ + a] + bq[a] + bm[a] + bl[a];
        float wl[32];
#pragma unroll
        for (int f = 0; f < 32; f++) wl[f] = Wl[f * AD_ + a];
        for (int jj = 0; jj < 64; jj++) {
            int t = (tid >> 7) + jj * 2;
            const float4* lr = (const float4*)&s_loc[t * F_];
            float racc = cbase;
#pragma unroll
            for (int f4 = 0; f4 < 8; f4++) {
                float4 lv = lr[f4];
                racc += lv.x * wl[f4 * 4] + lv.y * wl[f4 * 4 + 1]
                      + lv.z * wl[f4 * 4 + 2] + lv.w * wl[f4 * 4 + 3];
            }
            s_base[t * AD_ + a] = f2bf_rn(racc);
        }
    }
    __syncthreads();

    // ---- barrier-free MFMA K-loop: wave owns rows w*32..+31, all 128 cols ----
    const unsigned short* bp = wmT_sw + (long)lane * 8;

    f32x16 c0, c1, c2, c3;
#pragma unroll
    for (int i = 0; i < 16; i++) { c0[i] = 0.f; c1[i] = 0.f; c2[i] = 0.f; c3[i] = 0.f; }

#pragma unroll 2
    for (int c = 0; c < 16; c += 2) {
        {   // chunk c (regs p0x), refill with chunk c+2
            uint4v af0, af1;
            af0[0] = pk_bf2(p00.x, p00.y); af0[1] = pk_bf2(p00.z, p00.w);
            af0[2] = pk_bf2(p01.x, p01.y); af0[3] = pk_bf2(p01.z, p01.w);
            af1[0] = pk_bf2(p02.x, p02.y); af1[1] = pk_bf2(p02.z, p02.w);
            af1[2] = pk_bf2(p03.x, p03.y); af1[3] = pk_bf2(p03.z, p03.w);
            int kc = (c + 2 < 16) ? (c + 2) * 32 : 0;
            p00 = *(const float4*)(aRow + kc);
            p01 = *(const float4*)(aRow + kc + 4);
            p02 = *(const float4*)(aRow + kc + 16);
            p03 = *(const float4*)(aRow + kc + 20);
            const unsigned short* bb = bp + (long)(8 * c) * 512;
            uint4v B00 = *(const uint4v*)(bb);
            uint4v B01 = *(const uint4v*)(bb + 512);
            uint4v B02 = *(const uint4v*)(bb + 1024);
            uint4v B03 = *(const uint4v*)(bb + 1536);
            uint4v B10 = *(const uint4v*)(bb + 2048);
            uint4v B11 = *(const uint4v*)(bb + 2560);
            uint4v B12 = *(const uint4v*)(bb + 3072);
            uint4v B13 = *(const uint4v*)(bb + 3584);
            mfma32(c0, af0, B00); mfma32(c1, af0, B01);
            mfma32(c2, af0, B02); mfma32(c3, af0, B03);
            mfma32(c0, af1, B10); mfma32(c1, af1, B11);
            mfma32(c2, af1, B12); mfma32(c3, af1, B13);
        }
        {   // chunk c+1 (regs p1x), refill with chunk c+3
            uint4v af0, af1;
            af0[0] = pk_bf2(p10.x, p10.y); af0[1] = pk_bf2(p10.z, p10.w);
            af0[2] = pk_bf2(p11.x, p11.y); af0[3] = pk_bf2(p11.z, p11.w);
            af1[0] = pk_bf2(p12.x, p12.y); af1[1] = pk_bf2(p12.z, p12.w);
            af1[2] = pk_bf2(p13.x, p13.y); af1[3] = pk_bf2(p13.z, p13.w);
            int kc = (c + 3 < 16) ? (c + 3) * 32 : 0;
            p10 = *(const float4*)(aRow + kc);
            p11 = *(const float4*)(aRow + kc + 4);
            p12 = *(const float4*)(aRow + kc + 16);
            p13 = *(const float4*)(aRow + kc + 20);
            const unsigned short* bb = bp + (long)(8 * c + 8) * 512;
            uint4v B00 = *(const uint4v*)(bb);
            uint4v B01 = *(const uint4v*)(bb + 512);
            uint4v B02 = *(const uint4v*)(bb + 1024);
            uint4v B03 = *(const uint4v*)(bb + 1536);
            uint4v B10 = *(const uint4v*)(bb + 2048);
            uint4v B11 = *(const uint4v*)(bb + 2560);
            uint4v B12 = *(const uint4v*)(bb + 3072);
            uint4v B13 = *(const uint4v*)(bb + 3584);
            mfma32(c0, af0, B00); mfma32(c1, af0, B01);
            mfma32(c2, af0, B02); mfma32(c3, af0, B03);
            mfma32(c0, af1, B10); mfma32(c1, af1, B11);
            mfma32(c2, af1, B12); mfma32(c3, af1, B13);
        }
    }
    // drain MFMA->VALU hazard (inline asm bypasses compiler hazard recognizer)
    asm volatile("s_nop 7\n\ts_nop 7\n\ts_nop 7" ::: "memory");

    // ---- epilogue: tanh, dot with v, wave-reduce over cols ----
    {
        float vw0 = vw[l31], vw1 = vw[32 + l31], vw2 = vw[64 + l31], vw3 = vw[96 + l31];
#pragma unroll
        for (int i = 0; i < 16; i++) {
            int rl = (i & 3) + 8 * (i >> 2) + 4 * half;
            int r = w * 32 + rl;
            const unsigned short* br = &s_base[r * AD_ + l31];
            float s = fast_tanh(c0[i] + bf2f(br[0]))   * vw0
                    + fast_tanh(c1[i] + bf2f(br[32]))  * vw1
                    + fast_tanh(c2[i] + bf2f(br[64]))  * vw2
                    + fast_tanh(c3[i] + bf2f(br[96]))  * vw3;
            s += __shfl_xor(s, 1);
            s += __shfl_xor(s, 2);
            s += __shfl_xor(s, 4);
            s += __shfl_xor(s, 8);
            s += __shfl_xor(s, 16);
            if (l31 == 0) s_score[r] = s;
        }
    }
    __syncthreads();

    // ---- local softmax stats (wave 0 handles 128 rows) ----
    if (tid < 64) {
        float s0v = s_score[tid] + vb[0];
        float s1v = s_score[tid + 64] + vb[0];
        if (mask[(long)b * T_ + t0 + tid]) s0v = -INFINITY;
        if (mask[(long)b * T_ + t0 + 64 + tid]) s1v = -INFINITY;
        scores[b * T_ + t0 + tid] = s0v;
        scores[b * T_ + t0 + 64 + tid] = s1v;
        float m = fmaxf(s0v, s1v);
#pragma unroll
        for (int off = 32; off >= 1; off >>= 1) m = fmaxf(m, __shfl_xor(m, off));
        float e0 = (m == -INFINITY) ? 0.f : __expf(s0v - m);
        float e1 = (m == -INFINITY) ? 0.f : __expf(s1v - m);
        float d = e0 + e1;
#pragma unroll
        for (int off = 32; off >= 1; off >>= 1) d += __shfl_xor(d, off);
        s_w[tid] = e0;
        s_w[tid + 64] = e1;
        if (tid == 0) {
            bmax[b * NBLK + blk] = m;
            bden[b * NBLK + blk] = d;
        }
    }
    __syncthreads();

    // ---- partial context: num[md] = sum_t e^{s_t-m} * mem[t][md] (tile re-read, L2/L3-hot) ----
    {
        const float2* mp = (const float2*)(memory + ((long)b * T_ + t0) * MD_) + tid;
        float ax = 0.f, ay = 0.f;
#pragma unroll 8
        for (int t = 0; t < TT; t++) {
            float2 v = mp[(long)t * 256];
            float wt = s_w[t];
            ax += wt * v.x;
            ay += wt * v.y;
        }
        float2 o; o.x = ax; o.y = ay;
        *(float2*)(num + ((long)b * NBLK + blk) * MD_ + tid * 2) = o;
    }
}

// ---------------- K3: combine partials -> ctx + oalign ----------------
__global__ __launch_bounds__(512) void k_reduce(
    const float* __restrict__ bmax, const float* __restrict__ bden,
    const float* __restrict__ num, const float* __restrict__ scores,
    float* __restrict__ ctx, float* __restrict__ oalign) {
    int b = blockIdx.x;
    int tid = threadIdx.x;
    __shared__ float sm[NBLK], se[NBLK];
    __shared__ float sD;
    if (tid < NBLK) sm[tid] = bmax[b * NBLK + tid];
    __syncthreads();
    float M = -INFINITY;
#pragma unroll
    for (int i = 0; i < NBLK; i++) M = fmaxf(M, sm[i]);
    if (tid < NBLK) se[tid] = __expf(sm[tid] - M) * bden[b * NBLK + tid];
    __syncthreads();
    if (tid == 0) {
        float D = 0.f;
        for (int i = 0; i < NBLK; i++) D += se[i];
        sD = D;
    }
    __syncthreads();
    if (tid < NBLK) se[tid] = __expf(sm[tid] - M);   // scale factors
    __syncthreads();
    float invD = 1.f / sD;

    // ctx: one md per thread
    float acc = 0.f;
    const float* np = num + (long)b * NBLK * MD_ + tid;
#pragma unroll 8
    for (int blk = 0; blk < NBLK; blk++) acc += se[blk] * np[blk * MD_];
    ctx[b * MD_ + tid] = acc * invD;

    // alignments
    for (int t = tid; t < T_; t += 512) {
        oalign[b * T_ + t] = __expf(scores[b * T_ + t] - M) * invD;
    }
}

extern "C" void kernel_launch(void* const* d_in, const int* in_sizes, int n_in,
                              void* d_out, int out_size, void* d_ws, size_t ws_size,
                              hipStream_t stream) {
    const float* query      = (const float*)d_in[0];
    const float* memory     = (const float*)d_in[1];
    const float* alignments = (const float*)d_in[2];
    const unsigned char* mask = (const unsigned char*)d_in[3];
    const float* Wq    = (const float*)d_in[4];
    const float* bq    = (const float*)d_in[5];
    const float* Wm    = (const float*)d_in[6];
    const float* bm    = (const float*)d_in[7];
    const float* convw = (const float*)d_in[8];
    const float* convb = (const float*)d_in[9];
    const float* Wl    = (const float*)d_in[10];
    const float* bl    = (const float*)d_in[11];
    const float* vw    = (const float*)d_in[12];
    const float* vb    = (const float*)d_in[13];

    float* out = (float*)d_out;
    float* ctx = out;                      // [B,MD]
    float* oalign = out + B_ * MD_;        // [B,T]

    float* ws = (float*)d_ws;
    float* pq     = ws;                               // 4096 floats
    float* scores = pq + B_ * AD_;                    // 131072 floats
    float* bmax   = scores + B_ * T_;                 // 1024
    float* bden   = bmax + B_ * NBLK;                 // 1024
    float* num    = bden + B_ * NBLK;                 // 32*32*512 = 524288 floats
    unsigned short* wmT_sw = (unsigned short*)(num + (long)B_ * NBLK * MD_); // 65536 bf16

    hipMemsetAsync(pq, 0, B_ * AD_ * sizeof(float), stream);

    k_prep<<<32, 256, 0, stream>>>(Wm, wmT_sw);
    k_pq<<<dim3(B_, QD_ / 128), 128, 0, stream>>>(query, Wq, pq);
    k_score_ctx<<<dim3(NBLK, B_), 256, 0, stream>>>(
        memory, alignments, mask, wmT_sw, bm, convw, convb, Wl, bl, vw, vb, pq, bq,
        scores, bmax, bden, num);
    k_reduce<<<B_, 512, 0, stream>>>(bmax, bden, num, scores, ctx, oalign);
}